// Round 9
// baseline (132.703 us; speedup 1.0000x reference)
//
#include <hip/hip_runtime.h>

#define NB 256
#define NN 360
#define NF 360
#define NH 128
#define NKS 12   // 12 k-slices of 32 cover padded 384

using bf16x8 = __attribute__((ext_vector_type(8))) short;
using f32x4  = __attribute__((ext_vector_type(4))) float;

static __device__ __forceinline__ unsigned short f2bf(float f) {
  union { float f; unsigned u; } v; v.f = f;
  unsigned r = v.u + 0x7FFFu + ((v.u >> 16) & 1u);  // RNE
  return (unsigned short)(r >> 16);
}

static __device__ __forceinline__ bf16x8 pack8(float4 a, float4 b) {
  bf16x8 r;
  r[0] = (short)f2bf(a.x); r[1] = (short)f2bf(a.y);
  r[2] = (short)f2bf(a.z); r[3] = (short)f2bf(a.w);
  r[4] = (short)f2bf(b.x); r[5] = (short)f2bf(b.y);
  r[6] = (short)f2bf(b.z); r[7] = (short)f2bf(b.w);
  return r;
}

// chunk-linear tile offset: reader lane (lg*16+l15) gets chunk for (col n=ni*16+l15,
// k j=lg*8..+8) at ni*1024 + lane*16  (contiguous 1 KB/wave read, conflict-free)
static __device__ __forceinline__ int toff(int n, int j) {
  return ((n >> 4) << 10) + ((j >> 3) << 8) + ((n & 15) << 4) + ((j & 7) << 1);
}

// ---------------- K0: build chunk-linear kt-tiles of W1^T and W2^T ----------------------
__global__ void k_prep(const float* __restrict__ W1, const float* __restrict__ W2,
                       unsigned short* __restrict__ W1T, unsigned short* __restrict__ W2T) {
  const int t = blockIdx.x * 256 + threadIdx.x;     // 65536 = 12*4096 + 4*4096
  if (t < NKS * 4096) {
    const int ks = t >> 12, r = t & 4095;
    const int n = r >> 5, j = r & 31;               // n = hidden h, k = feat
    const int k = ks * 32 + j;
    const float v = (k < NF) ? W1[k * NH + n] : 0.f;
    *(unsigned short*)((char*)W1T + ks * 8192 + toff(n, j)) = f2bf(v);
  } else {
    const int t2 = t - NKS * 4096;
    const int ks = t2 >> 12, r = t2 & 4095;
    const int n = r >> 5, j = r & 31;               // n = out hidden, k = in hidden
    const int k = ks * 32 + j;
    *(unsigned short*)((char*)W2T + ks * 8192 + toff(n, j)) = f2bf(W2[k * NH + n]);
  }
}

#define RING_ISSUE(P0, P1, S, KK)                         \
  {                                                       \
    pfa[S][0] = *(const float4*)((P0) + (KK));            \
    pfb[S][0] = *(const float4*)((P0) + (KK) + 4);        \
    pfa[S][1] = *(const float4*)((P1) + (KK));            \
    pfb[S][1] = *(const float4*)((P1) + (KK) + 4);        \
  }

#define RING_ISSUE1(P1, S, KK)                            \
  {                                                       \
    pfa[S][1] = *(const float4*)((P1) + (KK));            \
    pfb[S][1] = *(const float4*)((P1) + (KK) + 4);        \
  }

// ---------------- fused per-batch kernel ------------------------------------------------
// LDS: panel 96 KB (phase A: XW1^T tiles; after B: H1W2^T tiles) | h1s 52.2 KB | ghl 6 KB
// LDS caps occupancy at 1 block/CU = 3 waves/EU; declare it so the register allocator
// uses the full 170-VGPR budget instead of spilling (R8: 84-VGPR pin + 37 MB scratch).
__global__ __launch_bounds__(768, 3) void k_fused(
    const float* __restrict__ x, const float* __restrict__ adj,
    const unsigned short* __restrict__ W1T, const unsigned short* __restrict__ W2T,
    const float* __restrict__ b1, const float* __restrict__ b2,
    float* __restrict__ out, float* __restrict__ gh) {
  const int b = blockIdx.x;
  const int tid = threadIdx.x;
  const int wid = tid >> 6, lane = tid & 63, l15 = lane & 15, lg = lane >> 4;
  extern __shared__ char smem[];
  char* panel = smem;                                             // 98304 B
  unsigned short* h1s = (unsigned short*)(smem + 98304) + wid * 2176;  // [16][136]/wave
  float* ghl = (float*)(smem + 98304 + 52224);                    // [12][128]

  const int kofs = lg * 8;
  const f32x4 fz = {0.f, 0.f, 0.f, 0.f};
  const bf16x8 bz = {0, 0, 0, 0, 0, 0, 0, 0};

  float b1v[8], b2v[8];
#pragma unroll
  for (int ni = 0; ni < 8; ++ni) {
    b1v[ni] = b1[ni * 16 + l15];
    b2v[ni] = b2[ni * 16 + l15];
  }

  f32x4 acc[2][8];
  float4 pfa[3][2], pfb[3][2];

  // =============== PHASE A: panel = (x@W1)^T ===============
  const int m0 = wid * 32 + l15, m1 = m0 + 16;
  const float* xr0 = x + ((size_t)b * NN + (m0 < NN ? m0 : NN - 1)) * NF;
  const float* xr1 = x + ((size_t)b * NN + (m1 < NN ? m1 : NN - 1)) * NF;

#pragma unroll
  for (int s = 0; s < 3; ++s) {
    int kk = s * 32 + kofs;
    RING_ISSUE(xr0, xr1, s, kk);
  }
#pragma unroll
  for (int i = 0; i < 2; ++i)
#pragma unroll
    for (int j = 0; j < 8; ++j) acc[i][j] = fz;

#pragma unroll
  for (int ks = 0; ks < NKS; ++ks) {
    const int d = ks % 3;
    const bool kv = (ks * 32 + kofs + 8) <= NF;
    bf16x8 br0 = kv ? pack8(pfa[d][0], pfb[d][0]) : bz;
    bf16x8 br1 = kv ? pack8(pfa[d][1], pfb[d][1]) : bz;
    if (ks + 3 < NKS) {
      int kk = (ks + 3) * 32 + kofs; kk = kk < 352 ? kk : 352;
      RING_ISSUE(xr0, xr1, d, kk);
    }
#pragma unroll
    for (int hi = 0; hi < 8; ++hi) {
      bf16x8 af = *(const bf16x8*)(W1T + ks * 4096 + hi * 512 + lane * 8);
      acc[0][hi] = __builtin_amdgcn_mfma_f32_16x16x32_bf16(af, br0, acc[0][hi], 0, 0, 0);
      acc[1][hi] = __builtin_amdgcn_mfma_f32_16x16x32_bf16(af, br1, acc[1][hi], 0, 0, 0);
    }
  }

  // panel1 write: value (h=hi*16+lg*4+r, m=wid*32+t*16+l15) -> tile wid, chunk-linear
  {
    char* pw = panel + wid * 8192 + (l15 >> 3) * 256 + (l15 & 7) * 2;
#pragma unroll
    for (int t = 0; t < 2; ++t) {
      const int m = wid * 32 + t * 16 + l15;
      const bool valid = m < NN;
#pragma unroll
      for (int hi = 0; hi < 8; ++hi)
#pragma unroll
        for (int r = 0; r < 4; ++r)
          *(unsigned short*)(pw + hi * 1024 + t * 512 + (lg * 4 + r) * 16) =
              valid ? f2bf(acc[t][hi][r]) : (unsigned short)0;
    }
  }
  __syncthreads();  // #1: panel1 ready

  // =============== PHASE B: H1 = relu(adj@XW1+b1); H1W2 -> regs ===============
  // adj bf16 fragments for the t=0 stream are RETAINED in aregB[] and reused in phase C
  const float* ar0 = adj + ((size_t)b * NN + (m0 < NN ? m0 : NN - 1)) * NN;
  const float* ar1 = adj + ((size_t)b * NN + (m1 < NN ? m1 : NN - 1)) * NN;

  bf16x8 aregB[NKS];

#pragma unroll
  for (int s = 0; s < 3; ++s) {
    int kk = s * 32 + kofs;
    RING_ISSUE(ar0, ar1, s, kk);
  }
#pragma unroll
  for (int i = 0; i < 2; ++i)
#pragma unroll
    for (int j = 0; j < 8; ++j) acc[i][j] = fz;

#pragma unroll
  for (int ks = 0; ks < NKS; ++ks) {
    const int d = ks % 3;
    const bool kv = (ks * 32 + kofs + 8) <= NN;
    bf16x8 br0 = kv ? pack8(pfa[d][0], pfb[d][0]) : bz;
    bf16x8 br1 = kv ? pack8(pfa[d][1], pfb[d][1]) : bz;
    aregB[ks] = br0;                                 // cache t=0 stream for phase C
    if (ks + 3 < NKS) {
      int kk = (ks + 3) * 32 + kofs; kk = kk < 352 ? kk : 352;
      RING_ISSUE(ar0, ar1, d, kk);
    }
#pragma unroll
    for (int ni = 0; ni < 8; ++ni) {
      bf16x8 bfv = *(const bf16x8*)(panel + ks * 8192 + ni * 1024 + lane * 16);
      acc[0][ni] = __builtin_amdgcn_mfma_f32_16x16x32_bf16(br0, bfv, acc[0][ni], 0, 0, 0);
      acc[1][ni] = __builtin_amdgcn_mfma_f32_16x16x32_bf16(br1, bfv, acc[1][ni], 0, 0, 0);
    }
  }

  // epilogue: bias+relu+mask, gh1 partials, per-wave transpose, GEMM2 -> packed ph
  float sgh[8];
#pragma unroll
  for (int ni = 0; ni < 8; ++ni) sgh[ni] = 0.f;
  unsigned ph[2][8][2];
#pragma unroll
  for (int t = 0; t < 2; ++t) {
#pragma unroll
    for (int ni = 0; ni < 8; ++ni) {
      const float bias = b1v[ni];
      float ssum = 0.f;
#pragma unroll
      for (int r = 0; r < 4; ++r) {
        const int orow = wid * 32 + t * 16 + lg * 4 + r;
        float h = acc[t][ni][r] + bias;
        h = h > 0.f ? h : 0.f;
        if (orow >= NN) h = 0.f;
        h1s[(lg * 4 + r) * 136 + ni * 16 + l15] = f2bf(h);
        ssum += h;
      }
      ssum += __shfl_xor(ssum, 16);
      ssum += __shfl_xor(ssum, 32);
      sgh[ni] += ssum;                               // meaningful on lg==0 lanes
    }
    f32x4 acc2[8];
#pragma unroll
    for (int j = 0; j < 8; ++j) acc2[j] = fz;
#pragma unroll
    for (int ks2 = 0; ks2 < 4; ++ks2) {
      bf16x8 a2 = *(const bf16x8*)&h1s[l15 * 136 + ks2 * 32 + lg * 8];
#pragma unroll
      for (int ni = 0; ni < 8; ++ni) {
        bf16x8 b2f = *(const bf16x8*)(W2T + ks2 * 4096 + ni * 512 + lane * 8);
        acc2[ni] = __builtin_amdgcn_mfma_f32_16x16x32_bf16(a2, b2f, acc2[ni], 0, 0, 0);
      }
    }
#pragma unroll
    for (int ni = 0; ni < 8; ++ni) {
      ph[t][ni][0] = (unsigned)f2bf(acc2[ni][0]) | ((unsigned)f2bf(acc2[ni][1]) << 16);
      ph[t][ni][1] = (unsigned)f2bf(acc2[ni][2]) | ((unsigned)f2bf(acc2[ni][3]) << 16);
    }
  }
  if (lg == 0) {
#pragma unroll
    for (int ni = 0; ni < 8; ++ni) ghl[wid * 128 + ni * 16 + l15] = sgh[ni];
  }
  __syncthreads();  // #2: panel1 fully consumed, ghl1 ready

  // head-start: issue phase-C ring (t=1 stream only) so latency hides under panel2 write
#pragma unroll
  for (int s = 0; s < 3; ++s) {
    int kk = s * 32 + kofs;
    RING_ISSUE1(ar1, s, kk);
  }

  // panel2 overwrite: value (n=wid*32+t*16+lg*4+r, j=ni*16+l15), b64 packed (r=0..3)
  {
    char* pw2 = panel + wid * 8192 + (lg >> 1) * 256 + l15 * 16 + (lg & 1) * 8;
#pragma unroll
    for (int t = 0; t < 2; ++t)
#pragma unroll
      for (int ni = 0; ni < 8; ++ni)
        *(uint2*)(pw2 + ni * 1024 + t * 512) = make_uint2(ph[t][ni][0], ph[t][ni][1]);
  }
  if (tid < 128) {
    float s = 0.f;
#pragma unroll
    for (int w = 0; w < 12; ++w) s += ghl[w * 128 + tid];
    gh[b * 256 + tid] = s;
  }
  __syncthreads();  // #3: panel2 ready

  // =============== PHASE C: H2 = relu(adj@H1W2+b2) -> out; gh2 ===============
  // t=0 stream comes from aregB (no loads); t=1 streams through the ring
#pragma unroll
  for (int i = 0; i < 2; ++i)
#pragma unroll
    for (int j = 0; j < 8; ++j) acc[i][j] = fz;

#pragma unroll
  for (int ks = 0; ks < NKS; ++ks) {
    const int d = ks % 3;
    const bool kv = (ks * 32 + kofs + 8) <= NN;
    bf16x8 br0 = aregB[ks];
    bf16x8 br1 = kv ? pack8(pfa[d][1], pfb[d][1]) : bz;
    if (ks + 3 < NKS) {
      int kk = (ks + 3) * 32 + kofs; kk = kk < 352 ? kk : 352;
      RING_ISSUE1(ar1, d, kk);
    }
#pragma unroll
    for (int ni = 0; ni < 8; ++ni) {
      bf16x8 bfv = *(const bf16x8*)(panel + ks * 8192 + ni * 1024 + lane * 16);
      acc[0][ni] = __builtin_amdgcn_mfma_f32_16x16x32_bf16(br0, bfv, acc[0][ni], 0, 0, 0);
      acc[1][ni] = __builtin_amdgcn_mfma_f32_16x16x32_bf16(br1, bfv, acc[1][ni], 0, 0, 0);
    }
  }

  float* outb = out + (size_t)b * NN * NH;
#pragma unroll
  for (int ni = 0; ni < 8; ++ni) sgh[ni] = 0.f;
#pragma unroll
  for (int t = 0; t < 2; ++t) {
#pragma unroll
    for (int ni = 0; ni < 8; ++ni) {
      const float bias = b2v[ni];
      float ssum = 0.f;
#pragma unroll
      for (int r = 0; r < 4; ++r) {
        const int orow = wid * 32 + t * 16 + lg * 4 + r;
        float h = acc[t][ni][r] + bias;
        h = h > 0.f ? h : 0.f;
        if (orow < NN) {
          outb[orow * NH + ni * 16 + l15] = h;
          ssum += h;
        }
      }
      ssum += __shfl_xor(ssum, 16);
      ssum += __shfl_xor(ssum, 32);
      sgh[ni] += ssum;
    }
  }
  if (lg == 0) {
#pragma unroll
    for (int ni = 0; ni < 8; ++ni) ghl[wid * 128 + ni * 16 + l15] = sgh[ni];
  }
  __syncthreads();  // #4
  if (tid < 128) {
    float s = 0.f;
#pragma unroll
    for (int w = 0; w < 12; ++w) s += ghl[w * 128 + tid];
    gh[b * 256 + 128 + tid] = s;
  }
}

extern "C" void kernel_launch(void* const* d_in, const int* in_sizes, int n_in,
                              void* d_out, int out_size, void* d_ws, size_t ws_size,
                              hipStream_t stream) {
  const float* x   = (const float*)d_in[0];
  const float* adj = (const float*)d_in[1];
  const float* W1  = (const float*)d_in[2];
  const float* b1  = (const float*)d_in[3];
  const float* W2  = (const float*)d_in[4];
  const float* b2  = (const float*)d_in[5];
  float* out = (float*)d_out;                       // h2 [256,360,128] then gh [256,256]
  float* gh  = out + (size_t)NB * NN * NH;

  char* ws = (char*)d_ws;
  unsigned short* W1T = (unsigned short*)ws;                // 98,304 B
  unsigned short* W2T = (unsigned short*)(ws + 98304);      // 32,768 B

  const int smem_bytes = 98304 + 52224 + 6144;              // 156,672 B
  hipFuncSetAttribute((const void*)k_fused, hipFuncAttributeMaxDynamicSharedMemorySize,
                      smem_bytes);

  k_prep <<<256, 256, 0, stream>>>(W1, W2, W1T, W2T);
  k_fused<<<NB, 768, smem_bytes, stream>>>(x, adj, W1T, W2T, b1, b2, out, gh);
}

// Round 10
// 111.334 us; speedup vs baseline: 1.1919x; 1.1919x over previous
//
#include <hip/hip_runtime.h>

#define NB 256
#define NN 360
#define NF 360
#define NH 128
#define NKS 12   // 12 k-slices of 32 cover padded 384

using bf16x8 = __attribute__((ext_vector_type(8))) short;
using f32x4  = __attribute__((ext_vector_type(4))) float;

static __device__ __forceinline__ unsigned short f2bf(float f) {
  union { float f; unsigned u; } v; v.f = f;
  unsigned r = v.u + 0x7FFFu + ((v.u >> 16) & 1u);  // RNE
  return (unsigned short)(r >> 16);
}

static __device__ __forceinline__ bf16x8 pack8(float4 a, float4 b) {
  bf16x8 r;
  r[0] = (short)f2bf(a.x); r[1] = (short)f2bf(a.y);
  r[2] = (short)f2bf(a.z); r[3] = (short)f2bf(a.w);
  r[4] = (short)f2bf(b.x); r[5] = (short)f2bf(b.y);
  r[6] = (short)f2bf(b.z); r[7] = (short)f2bf(b.w);
  return r;
}

// chunk-linear tile offset: reader lane (lg*16+l15) gets chunk for (col n=ni*16+l15,
// k j=lg*8..+8) at ni*1024 + lane*16  (contiguous 1 KB/wave read, conflict-free)
static __device__ __forceinline__ int toff(int n, int j) {
  return ((n >> 4) << 10) + ((j >> 3) << 8) + ((n & 15) << 4) + ((j & 7) << 1);
}

// ---------------- K0: build chunk-linear kt-tiles of W1^T and W2^T ----------------------
__global__ void k_prep(const float* __restrict__ W1, const float* __restrict__ W2,
                       unsigned short* __restrict__ W1T, unsigned short* __restrict__ W2T) {
  const int t = blockIdx.x * 256 + threadIdx.x;     // 65536 = 12*4096 + 4*4096
  if (t < NKS * 4096) {
    const int ks = t >> 12, r = t & 4095;
    const int n = r >> 5, j = r & 31;               // n = hidden h, k = feat
    const int k = ks * 32 + j;
    const float v = (k < NF) ? W1[k * NH + n] : 0.f;
    *(unsigned short*)((char*)W1T + ks * 8192 + toff(n, j)) = f2bf(v);
  } else {
    const int t2 = t - NKS * 4096;
    const int ks = t2 >> 12, r = t2 & 4095;
    const int n = r >> 5, j = r & 31;               // n = out hidden, k = in hidden
    const int k = ks * 32 + j;
    *(unsigned short*)((char*)W2T + ks * 8192 + toff(n, j)) = f2bf(W2[k * NH + n]);
  }
}

// 1-deep prefetch: four NAMED float4 regs (qa0/qb0 = stream0, qa1/qb1 = stream1).
#define PF_LOAD(P0, P1, KK)                  \
  {                                          \
    qa0 = *(const float4*)((P0) + (KK));     \
    qb0 = *(const float4*)((P0) + (KK) + 4); \
    qa1 = *(const float4*)((P1) + (KK));     \
    qb1 = *(const float4*)((P1) + (KK) + 4); \
  }

// ---------------- fused per-batch kernel ------------------------------------------------
// LDS: panel 96 KB (phase A: XW1^T tiles; after B: H1W2^T tiles) | h1s 52.2 KB | ghl 6 KB
// 156 KB LDS -> 1 block/CU -> 12 waves must co-reside -> VGPR must stay <=170: declare it.
__global__ __launch_bounds__(768, 3) void k_fused(
    const float* __restrict__ x, const float* __restrict__ adj,
    const unsigned short* __restrict__ W1T, const unsigned short* __restrict__ W2T,
    const float* __restrict__ b1, const float* __restrict__ b2,
    float* __restrict__ out, float* __restrict__ gh) {
  const int b = blockIdx.x;
  const int tid = threadIdx.x;
  const int wid = tid >> 6, lane = tid & 63, l15 = lane & 15, lg = lane >> 4;
  extern __shared__ char smem[];
  char* panel = smem;                                             // 98304 B
  unsigned short* h1s = (unsigned short*)(smem + 98304) + wid * 2176;  // [16][136]/wave
  float* ghl = (float*)(smem + 98304 + 52224);                    // [12][128]

  const int kofs = lg * 8;
  const f32x4 fz = {0.f, 0.f, 0.f, 0.f};
  const bf16x8 bz = {0, 0, 0, 0, 0, 0, 0, 0};

  f32x4 acc[2][8];
  float4 qa0, qb0, qa1, qb1;

  // =============== PHASE A: panel = (x@W1)^T ===============
  const int m0 = wid * 32 + l15, m1 = m0 + 16;
  const float* xr0 = x + ((size_t)b * NN + (m0 < NN ? m0 : NN - 1)) * NF;
  const float* xr1 = x + ((size_t)b * NN + (m1 < NN ? m1 : NN - 1)) * NF;

  PF_LOAD(xr0, xr1, kofs);
#pragma unroll
  for (int i = 0; i < 2; ++i)
#pragma unroll
    for (int j = 0; j < 8; ++j) acc[i][j] = fz;

#pragma unroll
  for (int ks = 0; ks < NKS; ++ks) {
    const bool kv = (ks * 32 + kofs + 8) <= NF;
    bf16x8 br0 = kv ? pack8(qa0, qb0) : bz;
    bf16x8 br1 = kv ? pack8(qa1, qb1) : bz;
    if (ks + 1 < NKS) {
      int kk = (ks + 1) * 32 + kofs; kk = kk < 352 ? kk : 352;
      PF_LOAD(xr0, xr1, kk);
    }
#pragma unroll
    for (int hi = 0; hi < 8; ++hi) {
      bf16x8 af = *(const bf16x8*)(W1T + ks * 4096 + hi * 512 + lane * 8);
      acc[0][hi] = __builtin_amdgcn_mfma_f32_16x16x32_bf16(af, br0, acc[0][hi], 0, 0, 0);
      acc[1][hi] = __builtin_amdgcn_mfma_f32_16x16x32_bf16(af, br1, acc[1][hi], 0, 0, 0);
    }
  }

  // panel1 write: value (h=hi*16+lg*4+r, m=wid*32+t*16+l15) -> tile wid, chunk-linear
  {
    char* pw = panel + wid * 8192 + (l15 >> 3) * 256 + (l15 & 7) * 2;
#pragma unroll
    for (int t = 0; t < 2; ++t) {
      const int m = wid * 32 + t * 16 + l15;
      const bool valid = m < NN;
#pragma unroll
      for (int hi = 0; hi < 8; ++hi)
#pragma unroll
        for (int r = 0; r < 4; ++r)
          *(unsigned short*)(pw + hi * 1024 + t * 512 + (lg * 4 + r) * 16) =
              valid ? f2bf(acc[t][hi][r]) : (unsigned short)0;
    }
  }
  __syncthreads();  // #1: panel1 ready

  // =============== PHASE B: H1 = relu(adj@XW1+b1); H1W2 -> regs ===============
  const float* ar0 = adj + ((size_t)b * NN + (m0 < NN ? m0 : NN - 1)) * NN;
  const float* ar1 = adj + ((size_t)b * NN + (m1 < NN ? m1 : NN - 1)) * NN;

  PF_LOAD(ar0, ar1, kofs);
#pragma unroll
  for (int i = 0; i < 2; ++i)
#pragma unroll
    for (int j = 0; j < 8; ++j) acc[i][j] = fz;

#pragma unroll
  for (int ks = 0; ks < NKS; ++ks) {
    const bool kv = (ks * 32 + kofs + 8) <= NN;
    bf16x8 br0 = kv ? pack8(qa0, qb0) : bz;
    bf16x8 br1 = kv ? pack8(qa1, qb1) : bz;
    if (ks + 1 < NKS) {
      int kk = (ks + 1) * 32 + kofs; kk = kk < 352 ? kk : 352;
      PF_LOAD(ar0, ar1, kk);
    }
#pragma unroll
    for (int ni = 0; ni < 8; ++ni) {
      bf16x8 bfv = *(const bf16x8*)(panel + ks * 8192 + ni * 1024 + lane * 16);
      acc[0][ni] = __builtin_amdgcn_mfma_f32_16x16x32_bf16(br0, bfv, acc[0][ni], 0, 0, 0);
      acc[1][ni] = __builtin_amdgcn_mfma_f32_16x16x32_bf16(br1, bfv, acc[1][ni], 0, 0, 0);
    }
  }

  // epilogue: bias+relu+mask, gh1 partials, per-wave transpose, GEMM2 -> packed ph
  float b1v[8];
#pragma unroll
  for (int ni = 0; ni < 8; ++ni) b1v[ni] = b1[ni * 16 + l15];
  float sgh[8];
#pragma unroll
  for (int ni = 0; ni < 8; ++ni) sgh[ni] = 0.f;
  unsigned ph[2][8][2];
#pragma unroll
  for (int t = 0; t < 2; ++t) {
#pragma unroll
    for (int ni = 0; ni < 8; ++ni) {
      const float bias = b1v[ni];
      float ssum = 0.f;
#pragma unroll
      for (int r = 0; r < 4; ++r) {
        const int orow = wid * 32 + t * 16 + lg * 4 + r;
        float h = acc[t][ni][r] + bias;
        h = h > 0.f ? h : 0.f;
        if (orow >= NN) h = 0.f;
        h1s[(lg * 4 + r) * 136 + ni * 16 + l15] = f2bf(h);
        ssum += h;
      }
      ssum += __shfl_xor(ssum, 16);
      ssum += __shfl_xor(ssum, 32);
      sgh[ni] += ssum;                               // meaningful on lg==0 lanes
    }
    f32x4 acc2[8];
#pragma unroll
    for (int j = 0; j < 8; ++j) acc2[j] = fz;
#pragma unroll
    for (int ks2 = 0; ks2 < 4; ++ks2) {
      bf16x8 a2 = *(const bf16x8*)&h1s[l15 * 136 + ks2 * 32 + lg * 8];
#pragma unroll
      for (int ni = 0; ni < 8; ++ni) {
        bf16x8 b2f = *(const bf16x8*)(W2T + ks2 * 4096 + ni * 512 + lane * 8);
        acc2[ni] = __builtin_amdgcn_mfma_f32_16x16x32_bf16(a2, b2f, acc2[ni], 0, 0, 0);
      }
    }
#pragma unroll
    for (int ni = 0; ni < 8; ++ni) {
      ph[t][ni][0] = (unsigned)f2bf(acc2[ni][0]) | ((unsigned)f2bf(acc2[ni][1]) << 16);
      ph[t][ni][1] = (unsigned)f2bf(acc2[ni][2]) | ((unsigned)f2bf(acc2[ni][3]) << 16);
    }
  }
  if (lg == 0) {
#pragma unroll
    for (int ni = 0; ni < 8; ++ni) ghl[wid * 128 + ni * 16 + l15] = sgh[ni];
  }
  __syncthreads();  // #2: panel1 fully consumed, ghl1 ready

  // phase-C first prefetch issued early: latency hides under panel2 write + gh store
  PF_LOAD(ar0, ar1, kofs);

  // panel2 overwrite: value (n=wid*32+t*16+lg*4+r, j=ni*16+l15), b64 packed (r=0..3)
  {
    char* pw2 = panel + wid * 8192 + (lg >> 1) * 256 + l15 * 16 + (lg & 1) * 8;
#pragma unroll
    for (int t = 0; t < 2; ++t)
#pragma unroll
      for (int ni = 0; ni < 8; ++ni)
        *(uint2*)(pw2 + ni * 1024 + t * 512) = make_uint2(ph[t][ni][0], ph[t][ni][1]);
  }
  if (tid < 128) {
    float s = 0.f;
#pragma unroll
    for (int w = 0; w < 12; ++w) s += ghl[w * 128 + tid];
    gh[b * 256 + tid] = s;
  }
  __syncthreads();  // #3: panel2 ready

  // =============== PHASE C: H2 = relu(adj@H1W2+b2) -> out; gh2 ===============
#pragma unroll
  for (int i = 0; i < 2; ++i)
#pragma unroll
    for (int j = 0; j < 8; ++j) acc[i][j] = fz;

#pragma unroll
  for (int ks = 0; ks < NKS; ++ks) {
    const bool kv = (ks * 32 + kofs + 8) <= NN;
    bf16x8 br0 = kv ? pack8(qa0, qb0) : bz;
    bf16x8 br1 = kv ? pack8(qa1, qb1) : bz;
    if (ks + 1 < NKS) {
      int kk = (ks + 1) * 32 + kofs; kk = kk < 352 ? kk : 352;
      PF_LOAD(ar0, ar1, kk);
    }
#pragma unroll
    for (int ni = 0; ni < 8; ++ni) {
      bf16x8 bfv = *(const bf16x8*)(panel + ks * 8192 + ni * 1024 + lane * 16);
      acc[0][ni] = __builtin_amdgcn_mfma_f32_16x16x32_bf16(br0, bfv, acc[0][ni], 0, 0, 0);
      acc[1][ni] = __builtin_amdgcn_mfma_f32_16x16x32_bf16(br1, bfv, acc[1][ni], 0, 0, 0);
    }
  }

  float b2v[8];
#pragma unroll
  for (int ni = 0; ni < 8; ++ni) b2v[ni] = b2[ni * 16 + l15];
  float* outb = out + (size_t)b * NN * NH;
#pragma unroll
  for (int ni = 0; ni < 8; ++ni) sgh[ni] = 0.f;
#pragma unroll
  for (int t = 0; t < 2; ++t) {
#pragma unroll
    for (int ni = 0; ni < 8; ++ni) {
      const float bias = b2v[ni];
      float ssum = 0.f;
#pragma unroll
      for (int r = 0; r < 4; ++r) {
        const int orow = wid * 32 + t * 16 + lg * 4 + r;
        float h = acc[t][ni][r] + bias;
        h = h > 0.f ? h : 0.f;
        if (orow < NN) {
          outb[orow * NH + ni * 16 + l15] = h;
          ssum += h;
        }
      }
      ssum += __shfl_xor(ssum, 16);
      ssum += __shfl_xor(ssum, 32);
      sgh[ni] += ssum;
    }
  }
  if (lg == 0) {
#pragma unroll
    for (int ni = 0; ni < 8; ++ni) ghl[wid * 128 + ni * 16 + l15] = sgh[ni];
  }
  __syncthreads();  // #4
  if (tid < 128) {
    float s = 0.f;
#pragma unroll
    for (int w = 0; w < 12; ++w) s += ghl[w * 128 + tid];
    gh[b * 256 + 128 + tid] = s;
  }
}

extern "C" void kernel_launch(void* const* d_in, const int* in_sizes, int n_in,
                              void* d_out, int out_size, void* d_ws, size_t ws_size,
                              hipStream_t stream) {
  const float* x   = (const float*)d_in[0];
  const float* adj = (const float*)d_in[1];
  const float* W1  = (const float*)d_in[2];
  const float* b1  = (const float*)d_in[3];
  const float* W2  = (const float*)d_in[4];
  const float* b2  = (const float*)d_in[5];
  float* out = (float*)d_out;                       // h2 [256,360,128] then gh [256,256]
  float* gh  = out + (size_t)NB * NN * NH;

  char* ws = (char*)d_ws;
  unsigned short* W1T = (unsigned short*)ws;                // 98,304 B
  unsigned short* W2T = (unsigned short*)(ws + 98304);      // 32,768 B

  const int smem_bytes = 98304 + 52224 + 6144;              // 156,672 B
  hipFuncSetAttribute((const void*)k_fused, hipFuncAttributeMaxDynamicSharedMemorySize,
                      smem_bytes);

  k_prep <<<256, 256, 0, stream>>>(W1, W2, W1T, W2T);
  k_fused<<<NB, 768, smem_bytes, stream>>>(x, adj, W1T, W2T, b1, b2, out, gh);
}

// Round 11
// 111.259 us; speedup vs baseline: 1.1927x; 1.0007x over previous
//
#include <hip/hip_runtime.h>
#include <hip/hip_bf16.h>

#define NB 256
#define NN 360
#define NF 360
#define NH 128
#define NKS 12   // 12 k-slices of 32 cover padded 384

using bf16x8 = __attribute__((ext_vector_type(8))) short;
using f32x4  = __attribute__((ext_vector_type(4))) float;

static __device__ __forceinline__ unsigned short f2bf(float f) {
  union { float f; unsigned u; } v; v.f = f;
  unsigned r = v.u + 0x7FFFu + ((v.u >> 16) & 1u);  // RNE
  return (unsigned short)(r >> 16);
}

// pack 8 f32 -> 8 bf16 via HW v_cvt_pk_bf16_f32 (compiler-generated, RNE)
static __device__ __forceinline__ bf16x8 pack8(float4 a, float4 b) {
  union { __hip_bfloat162 h[4]; bf16x8 v; } z;
  z.h[0] = __float22bfloat162_rn(make_float2(a.x, a.y));
  z.h[1] = __float22bfloat162_rn(make_float2(a.z, a.w));
  z.h[2] = __float22bfloat162_rn(make_float2(b.x, b.y));
  z.h[3] = __float22bfloat162_rn(make_float2(b.z, b.w));
  return z.v;
}

// chunk-linear tile offset: reader lane (lg*16+l15) gets chunk for (col n=ni*16+l15,
// k j=lg*8..+8) at ni*1024 + lane*16  (contiguous 1 KB/wave read, conflict-free)
static __device__ __forceinline__ int toff(int n, int j) {
  return ((n >> 4) << 10) + ((j >> 3) << 8) + ((n & 15) << 4) + ((j & 7) << 1);
}

// ---------------- K0: build chunk-linear kt-tiles of W1^T and W2^T ----------------------
__global__ void k_prep(const float* __restrict__ W1, const float* __restrict__ W2,
                       unsigned short* __restrict__ W1T, unsigned short* __restrict__ W2T) {
  const int t = blockIdx.x * 256 + threadIdx.x;     // 65536 = 12*4096 + 4*4096
  if (t < NKS * 4096) {
    const int ks = t >> 12, r = t & 4095;
    const int n = r >> 5, j = r & 31;               // n = hidden h, k = feat
    const int k = ks * 32 + j;
    const float v = (k < NF) ? W1[k * NH + n] : 0.f;
    *(unsigned short*)((char*)W1T + ks * 8192 + toff(n, j)) = f2bf(v);
  } else {
    const int t2 = t - NKS * 4096;
    const int ks = t2 >> 12, r = t2 & 4095;
    const int n = r >> 5, j = r & 31;               // n = out hidden, k = in hidden
    const int k = ks * 32 + j;
    *(unsigned short*)((char*)W2T + ks * 8192 + toff(n, j)) = f2bf(W2[k * NH + n]);
  }
}

// 2-deep prefetch into NAMED float4 regs (even/odd buffers, SSA-friendly)
#define PF2(A0, B0, A1, B1, P0, P1, KK)      \
  {                                          \
    A0 = *(const float4*)((P0) + (KK));      \
    B0 = *(const float4*)((P0) + (KK) + 4);  \
    A1 = *(const float4*)((P1) + (KK));      \
    B1 = *(const float4*)((P1) + (KK) + 4);  \
  }

// ---------------- fused per-batch kernel ------------------------------------------------
// LDS: panel 96 KB (phase A: XW1^T tiles; after B: H1W2^T tiles) | h1s 52.2 KB | ghl 6 KB
// 156 KB LDS -> 1 block/CU -> exactly 3 waves/EU: pin it so the allocator uses the full
// ~170-VGPR budget (launch_bounds min-waves hint was ignored; VGPR pinned 84 + spill).
__global__ __launch_bounds__(768)
__attribute__((amdgpu_waves_per_eu(3, 3))) void k_fused(
    const float* __restrict__ x, const float* __restrict__ adj,
    const unsigned short* __restrict__ W1T, const unsigned short* __restrict__ W2T,
    const float* __restrict__ b1, const float* __restrict__ b2,
    float* __restrict__ out, float* __restrict__ gh) {
  const int b = blockIdx.x;
  const int tid = threadIdx.x;
  const int wid = tid >> 6, lane = tid & 63, l15 = lane & 15, lg = lane >> 4;
  extern __shared__ char smem[];
  char* panel = smem;                                             // 98304 B
  unsigned short* h1s = (unsigned short*)(smem + 98304) + wid * 2176;  // [16][136]/wave
  float* ghl = (float*)(smem + 98304 + 52224);                    // [12][128]

  const int kofs = lg * 8;
  const f32x4 fz = {0.f, 0.f, 0.f, 0.f};
  const bf16x8 bz = {0, 0, 0, 0, 0, 0, 0, 0};

  f32x4 acc[2][8];
  float4 ea0, eb0, ea1, eb1, oa0, ob0, oa1, ob1;

  // =============== PHASE A: panel = (x@W1)^T ===============
  const int m0 = wid * 32 + l15, m1 = m0 + 16;
  const float* xr0 = x + ((size_t)b * NN + (m0 < NN ? m0 : NN - 1)) * NF;
  const float* xr1 = x + ((size_t)b * NN + (m1 < NN ? m1 : NN - 1)) * NF;

  PF2(ea0, eb0, ea1, eb1, xr0, xr1, kofs);
  PF2(oa0, ob0, oa1, ob1, xr0, xr1, 32 + kofs);
#pragma unroll
  for (int i = 0; i < 2; ++i)
#pragma unroll
    for (int j = 0; j < 8; ++j) acc[i][j] = fz;

#pragma unroll
  for (int ks = 0; ks < NKS; ++ks) {
    const bool kv = (ks * 32 + kofs + 8) <= NF;
    bf16x8 br0, br1;
    if (ks & 1) { br0 = kv ? pack8(oa0, ob0) : bz; br1 = kv ? pack8(oa1, ob1) : bz; }
    else        { br0 = kv ? pack8(ea0, eb0) : bz; br1 = kv ? pack8(ea1, eb1) : bz; }
    if (ks + 2 < NKS) {
      int kk = (ks + 2) * 32 + kofs; kk = kk < 352 ? kk : 352;
      if (ks & 1) { PF2(oa0, ob0, oa1, ob1, xr0, xr1, kk); }
      else        { PF2(ea0, eb0, ea1, eb1, xr0, xr1, kk); }
    }
#pragma unroll
    for (int hi = 0; hi < 8; ++hi) {
      bf16x8 af = *(const bf16x8*)(W1T + ks * 4096 + hi * 512 + lane * 8);
      acc[0][hi] = __builtin_amdgcn_mfma_f32_16x16x32_bf16(af, br0, acc[0][hi], 0, 0, 0);
      acc[1][hi] = __builtin_amdgcn_mfma_f32_16x16x32_bf16(af, br1, acc[1][hi], 0, 0, 0);
    }
  }

  // panel1 write: value (h=hi*16+lg*4+r, m=wid*32+t*16+l15) -> tile wid, chunk-linear
  {
    char* pw = panel + wid * 8192 + (l15 >> 3) * 256 + (l15 & 7) * 2;
#pragma unroll
    for (int t = 0; t < 2; ++t) {
      const int m = wid * 32 + t * 16 + l15;
      const bool valid = m < NN;
#pragma unroll
      for (int hi = 0; hi < 8; ++hi)
#pragma unroll
        for (int r = 0; r < 4; ++r)
          *(unsigned short*)(pw + hi * 1024 + t * 512 + (lg * 4 + r) * 16) =
              valid ? f2bf(acc[t][hi][r]) : (unsigned short)0;
    }
  }

  // phase-B head-start: adj loads are barrier-independent; cover latency with the barrier
  const float* ar0 = adj + ((size_t)b * NN + (m0 < NN ? m0 : NN - 1)) * NN;
  const float* ar1 = adj + ((size_t)b * NN + (m1 < NN ? m1 : NN - 1)) * NN;
  PF2(ea0, eb0, ea1, eb1, ar0, ar1, kofs);
  PF2(oa0, ob0, oa1, ob1, ar0, ar1, 32 + kofs);

  __syncthreads();  // #1: panel1 ready

  // =============== PHASE B: H1 = relu(adj@XW1+b1); H1W2 -> regs ===============
#pragma unroll
  for (int i = 0; i < 2; ++i)
#pragma unroll
    for (int j = 0; j < 8; ++j) acc[i][j] = fz;

#pragma unroll
  for (int ks = 0; ks < NKS; ++ks) {
    const bool kv = (ks * 32 + kofs + 8) <= NN;
    bf16x8 br0, br1;
    if (ks & 1) { br0 = kv ? pack8(oa0, ob0) : bz; br1 = kv ? pack8(oa1, ob1) : bz; }
    else        { br0 = kv ? pack8(ea0, eb0) : bz; br1 = kv ? pack8(ea1, eb1) : bz; }
    if (ks + 2 < NKS) {
      int kk = (ks + 2) * 32 + kofs; kk = kk < 352 ? kk : 352;
      if (ks & 1) { PF2(oa0, ob0, oa1, ob1, ar0, ar1, kk); }
      else        { PF2(ea0, eb0, ea1, eb1, ar0, ar1, kk); }
    }
#pragma unroll
    for (int ni = 0; ni < 8; ++ni) {
      bf16x8 bfv = *(const bf16x8*)(panel + ks * 8192 + ni * 1024 + lane * 16);
      acc[0][ni] = __builtin_amdgcn_mfma_f32_16x16x32_bf16(br0, bfv, acc[0][ni], 0, 0, 0);
      acc[1][ni] = __builtin_amdgcn_mfma_f32_16x16x32_bf16(br1, bfv, acc[1][ni], 0, 0, 0);
    }
  }

  // epilogue: bias+relu+mask, gh1 partials, per-wave transpose, GEMM2 -> packed ph
  float b1v[8];
#pragma unroll
  for (int ni = 0; ni < 8; ++ni) b1v[ni] = b1[ni * 16 + l15];
  float sgh[8];
#pragma unroll
  for (int ni = 0; ni < 8; ++ni) sgh[ni] = 0.f;
  unsigned ph[2][8][2];
#pragma unroll
  for (int t = 0; t < 2; ++t) {
#pragma unroll
    for (int ni = 0; ni < 8; ++ni) {
      const float bias = b1v[ni];
      float ssum = 0.f;
#pragma unroll
      for (int r = 0; r < 4; ++r) {
        const int orow = wid * 32 + t * 16 + lg * 4 + r;
        float h = acc[t][ni][r] + bias;
        h = h > 0.f ? h : 0.f;
        if (orow >= NN) h = 0.f;
        h1s[(lg * 4 + r) * 136 + ni * 16 + l15] = f2bf(h);
        ssum += h;
      }
      ssum += __shfl_xor(ssum, 16);
      ssum += __shfl_xor(ssum, 32);
      sgh[ni] += ssum;                               // meaningful on lg==0 lanes
    }
    f32x4 acc2[8];
#pragma unroll
    for (int j = 0; j < 8; ++j) acc2[j] = fz;
#pragma unroll
    for (int ks2 = 0; ks2 < 4; ++ks2) {
      bf16x8 a2 = *(const bf16x8*)&h1s[l15 * 136 + ks2 * 32 + lg * 8];
#pragma unroll
      for (int ni = 0; ni < 8; ++ni) {
        bf16x8 b2f = *(const bf16x8*)(W2T + ks2 * 4096 + ni * 512 + lane * 8);
        acc2[ni] = __builtin_amdgcn_mfma_f32_16x16x32_bf16(a2, b2f, acc2[ni], 0, 0, 0);
      }
    }
#pragma unroll
    for (int ni = 0; ni < 8; ++ni) {
      ph[t][ni][0] = (unsigned)f2bf(acc2[ni][0]) | ((unsigned)f2bf(acc2[ni][1]) << 16);
      ph[t][ni][1] = (unsigned)f2bf(acc2[ni][2]) | ((unsigned)f2bf(acc2[ni][3]) << 16);
    }
  }
  if (lg == 0) {
#pragma unroll
    for (int ni = 0; ni < 8; ++ni) ghl[wid * 128 + ni * 16 + l15] = sgh[ni];
  }
  __syncthreads();  // #2: panel1 fully consumed, ghl1 ready

  // phase-C head-start: same adj rows; latency hides under panel2 write + gh store
  PF2(ea0, eb0, ea1, eb1, ar0, ar1, kofs);
  PF2(oa0, ob0, oa1, ob1, ar0, ar1, 32 + kofs);

  // panel2 overwrite: value (n=wid*32+t*16+lg*4+r, j=ni*16+l15), b64 packed (r=0..3)
  {
    char* pw2 = panel + wid * 8192 + (lg >> 1) * 256 + l15 * 16 + (lg & 1) * 8;
#pragma unroll
    for (int t = 0; t < 2; ++t)
#pragma unroll
      for (int ni = 0; ni < 8; ++ni)
        *(uint2*)(pw2 + ni * 1024 + t * 512) = make_uint2(ph[t][ni][0], ph[t][ni][1]);
  }
  if (tid < 128) {
    float s = 0.f;
#pragma unroll
    for (int w = 0; w < 12; ++w) s += ghl[w * 128 + tid];
    gh[b * 256 + tid] = s;
  }
  __syncthreads();  // #3: panel2 ready

  // =============== PHASE C: H2 = relu(adj@H1W2+b2) -> out; gh2 ===============
#pragma unroll
  for (int i = 0; i < 2; ++i)
#pragma unroll
    for (int j = 0; j < 8; ++j) acc[i][j] = fz;

#pragma unroll
  for (int ks = 0; ks < NKS; ++ks) {
    const bool kv = (ks * 32 + kofs + 8) <= NN;
    bf16x8 br0, br1;
    if (ks & 1) { br0 = kv ? pack8(oa0, ob0) : bz; br1 = kv ? pack8(oa1, ob1) : bz; }
    else        { br0 = kv ? pack8(ea0, eb0) : bz; br1 = kv ? pack8(ea1, eb1) : bz; }
    if (ks + 2 < NKS) {
      int kk = (ks + 2) * 32 + kofs; kk = kk < 352 ? kk : 352;
      if (ks & 1) { PF2(oa0, ob0, oa1, ob1, ar0, ar1, kk); }
      else        { PF2(ea0, eb0, ea1, eb1, ar0, ar1, kk); }
    }
#pragma unroll
    for (int ni = 0; ni < 8; ++ni) {
      bf16x8 bfv = *(const bf16x8*)(panel + ks * 8192 + ni * 1024 + lane * 16);
      acc[0][ni] = __builtin_amdgcn_mfma_f32_16x16x32_bf16(br0, bfv, acc[0][ni], 0, 0, 0);
      acc[1][ni] = __builtin_amdgcn_mfma_f32_16x16x32_bf16(br1, bfv, acc[1][ni], 0, 0, 0);
    }
  }

  float b2v[8];
#pragma unroll
  for (int ni = 0; ni < 8; ++ni) b2v[ni] = b2[ni * 16 + l15];
  float* outb = out + (size_t)b * NN * NH;
#pragma unroll
  for (int ni = 0; ni < 8; ++ni) sgh[ni] = 0.f;
#pragma unroll
  for (int t = 0; t < 2; ++t) {
#pragma unroll
    for (int ni = 0; ni < 8; ++ni) {
      const float bias = b2v[ni];
      float ssum = 0.f;
#pragma unroll
      for (int r = 0; r < 4; ++r) {
        const int orow = wid * 32 + t * 16 + lg * 4 + r;
        float h = acc[t][ni][r] + bias;
        h = h > 0.f ? h : 0.f;
        if (orow < NN) {
          outb[orow * NH + ni * 16 + l15] = h;
          ssum += h;
        }
      }
      ssum += __shfl_xor(ssum, 16);
      ssum += __shfl_xor(ssum, 32);
      sgh[ni] += ssum;
    }
  }
  if (lg == 0) {
#pragma unroll
    for (int ni = 0; ni < 8; ++ni) ghl[wid * 128 + ni * 16 + l15] = sgh[ni];
  }
  __syncthreads();  // #4
  if (tid < 128) {
    float s = 0.f;
#pragma unroll
    for (int w = 0; w < 12; ++w) s += ghl[w * 128 + tid];
    gh[b * 256 + 128 + tid] = s;
  }
}

extern "C" void kernel_launch(void* const* d_in, const int* in_sizes, int n_in,
                              void* d_out, int out_size, void* d_ws, size_t ws_size,
                              hipStream_t stream) {
  const float* x   = (const float*)d_in[0];
  const float* adj = (const float*)d_in[1];
  const float* W1  = (const float*)d_in[2];
  const float* b1  = (const float*)d_in[3];
  const float* W2  = (const float*)d_in[4];
  const float* b2  = (const float*)d_in[5];
  float* out = (float*)d_out;                       // h2 [256,360,128] then gh [256,256]
  float* gh  = out + (size_t)NB * NN * NH;

  char* ws = (char*)d_ws;
  unsigned short* W1T = (unsigned short*)ws;                // 98,304 B
  unsigned short* W2T = (unsigned short*)(ws + 98304);      // 32,768 B

  const int smem_bytes = 98304 + 52224 + 6144;              // 156,672 B
  hipFuncSetAttribute((const void*)k_fused, hipFuncAttributeMaxDynamicSharedMemorySize,
                      smem_bytes);

  k_prep <<<256, 256, 0, stream>>>(W1, W2, W1T, W2T);
  k_fused<<<NB, 768, smem_bytes, stream>>>(x, adj, W1T, W2T, b1, b2, out, gh);
}